// Round 2
// 221.992 us; speedup vs baseline: 1.0119x; 1.0119x over previous
//
#include <hip/hip_runtime.h>

typedef __bf16 bhalf;
typedef __bf16 bhalf8 __attribute__((ext_vector_type(8)));
typedef __bf16 bhalf4 __attribute__((ext_vector_type(4)));
typedef float f32x4 __attribute__((ext_vector_type(4)));

typedef __attribute__((address_space(1))) const void* gas_p;
typedef __attribute__((address_space(3))) void* las_p;

#define T_SEQ 2048
#define HIDN  2048
#define NQH   32
#define NKVH  8
#define DH    64
#define NQKV  3072

// ---------------- elementwise cast fp32 -> bf16 ----------------
__global__ __launch_bounds__(256) void cast_bf16_k(const float* __restrict__ in,
                                                   bhalf* __restrict__ out, int n) {
  int i = (blockIdx.x * 256 + threadIdx.x) * 4;
  if (i + 3 < n) {
    float4 v = *(const float4*)(in + i);
    bhalf4 o;
    o[0] = (bhalf)v.x; o[1] = (bhalf)v.y; o[2] = (bhalf)v.z; o[3] = (bhalf)v.w;
    *(bhalf4*)(out + i) = o;
  }
}

// ---------------- transpose + cast fp32->bf16: out[C][R] = (bf16) in[R][C] -------------
__global__ __launch_bounds__(256) void transpose_cast_k(const float* __restrict__ in,
                                                        bhalf* __restrict__ out, int R, int C) {
  __shared__ float tile[32][33];
  int bx = blockIdx.x * 32;
  int by = blockIdx.y * 32;
  int tx = threadIdx.x & 31, ty = threadIdx.x >> 5;
#pragma unroll
  for (int p = 0; p < 4; ++p)
    tile[ty + 8 * p][tx] = in[(size_t)(by + ty + 8 * p) * C + bx + tx];
  __syncthreads();
#pragma unroll
  for (int p = 0; p < 4; ++p)
    out[(size_t)(bx + ty + 8 * p) * R + by + tx] = (bhalf)tile[tx][ty + 8 * p];
}

// ---------------- bf16 transpose: out[C][R] = in[R][C] ----------------
__global__ __launch_bounds__(256) void transpose_bf16_k(const bhalf* __restrict__ in,
                                                        bhalf* __restrict__ out, int R, int C) {
  __shared__ bhalf tile[32][33];
  int bx = blockIdx.x * 32;
  int by = blockIdx.y * 32;
  int tx = threadIdx.x & 31, ty = threadIdx.x >> 5;
#pragma unroll
  for (int p = 0; p < 4; ++p)
    tile[ty + 8 * p][tx] = in[(size_t)(by + ty + 8 * p) * C + bx + tx];
  __syncthreads();
#pragma unroll
  for (int p = 0; p < 4; ++p)
    out[(size_t)(bx + ty + 8 * p) * R + by + tx] = tile[tx][ty + 8 * p];
}

// ---------------- shared GEMM core: 128(M) x 64(N) tile, BK=64 ----------------
// 4 waves stacked in M (wave tile 32x64). XOR-swizzled LDS staged via
// global_load_lds width=16. Double-buffered: stage tile k+1 before
// computing tile k, so the vmcnt(0) drain at the loop-top barrier is covered
// by a full K-step of ds_read+MFMA instead of nothing.
__device__ __forceinline__ void gemm_core(const bhalf* __restrict__ A,
                                          const bhalf* __restrict__ Bt, int K,
                                          int bm, int bn, int tid,
                                          bhalf* As, bhalf* Bs, f32x4 acc[2][4]) {
  int lane = tid & 63, wv = tid >> 6;
  int m16 = lane & 15, q4 = lane >> 4;
  int srow = tid >> 3;                         // 0..31
  int scol = ((tid & 7) ^ (srow & 7)) * 8;     // XOR-swizzled source col block
  const bhalf* asrc = A + (size_t)(bm + srow) * K + scol;
  const bhalf* bsrc = Bt + (size_t)(bn + srow) * K + scol;
  bhalf* adst = As + (wv * 8) * 64;
  bhalf* bdst = Bs + (wv * 8) * 64;
  int swz = m16 & 7;

  auto stage = [&](int k0, int sbuf) {
#pragma unroll
    for (int c = 0; c < 4; ++c)
      __builtin_amdgcn_global_load_lds((gas_p)(asrc + (size_t)(c * 32) * K + k0),
                                       (las_p)(adst + sbuf * 8192 + c * 2048), 16, 0, 0);
#pragma unroll
    for (int c = 0; c < 2; ++c)
      __builtin_amdgcn_global_load_lds((gas_p)(bsrc + (size_t)(c * 32) * K + k0),
                                       (las_p)(bdst + sbuf * 4096 + c * 2048), 16, 0, 0);
  };

  stage(0, 0);
  int buf = 0;
  for (int k0 = 0; k0 < K; k0 += 64) {
    __syncthreads();  // drains vmcnt: buf's tile landed (issued one iter ago)
    if (k0 + 64 < K) stage(k0 + 64, buf ^ 1);
    const bhalf* Ab = As + buf * 8192;
    const bhalf* Bb = Bs + buf * 4096;
    bhalf8 af[2][2], bf[4][2];
#pragma unroll
    for (int mi = 0; mi < 2; ++mi)
#pragma unroll
      for (int ks = 0; ks < 2; ++ks)
        af[mi][ks] = *(const bhalf8*)&Ab[(wv * 32 + mi * 16 + m16) * 64 +
                                         (((ks * 4 + q4) ^ swz) * 8)];
#pragma unroll
    for (int ni = 0; ni < 4; ++ni)
#pragma unroll
      for (int ks = 0; ks < 2; ++ks)
        bf[ni][ks] = *(const bhalf8*)&Bb[(ni * 16 + m16) * 64 +
                                         (((ks * 4 + q4) ^ swz) * 8)];
#pragma unroll
    for (int mi = 0; mi < 2; ++mi)
#pragma unroll
      for (int ni = 0; ni < 4; ++ni) {
        acc[mi][ni] = __builtin_amdgcn_mfma_f32_16x16x32_bf16(af[mi][0], bf[ni][0], acc[mi][ni], 0, 0, 0);
        acc[mi][ni] = __builtin_amdgcn_mfma_f32_16x16x32_bf16(af[mi][1], bf[ni][1], acc[mi][ni], 0, 0, 0);
      }
    buf ^= 1;
  }
}

// ---------------- GEMM1 + fused RMSNorm + RoPE + split + cast ----------------
// N-tile 64 == one head (h = blockIdx.x: 0..31 q, 32..39 k, 40..47 v).
__global__ __launch_bounds__(256) void gemm1_fused_k(const bhalf* __restrict__ A,
                                                     const bhalf* __restrict__ Bt,
                                                     const int* __restrict__ pos,
                                                     const float* __restrict__ qw,
                                                     const float* __restrict__ kw,
                                                     bhalf* __restrict__ qo,
                                                     bhalf* __restrict__ ko,
                                                     bhalf* __restrict__ vo) {
  __shared__ __align__(16) bhalf As[2 * 128 * 64];
  __shared__ __align__(16) bhalf Bs[2 * 64 * 64];
  int tid = threadIdx.x, lane = tid & 63, wv = tid >> 6;
  int m16 = lane & 15, q4 = lane >> 4;
  int bm = blockIdx.y * 128, bn = blockIdx.x * 64, h = blockIdx.x;
  f32x4 zero4 = {0.f, 0.f, 0.f, 0.f};
  f32x4 acc[2][4];
#pragma unroll
  for (int mi = 0; mi < 2; ++mi)
#pragma unroll
    for (int ni = 0; ni < 4; ++ni) acc[mi][ni] = zero4;

  gemm_core(A, Bt, HIDN, bm, bn, tid, As, Bs, acc);

  int wr0 = wv * 32;
  if (h < 40) {
    float wd[4];
    const float* wptr = (h < 32) ? qw : kw;
#pragma unroll
    for (int ni = 0; ni < 4; ++ni) wd[ni] = wptr[ni * 16 + m16];
    float f0 = exp2f((float)m16 * -0.6228615177913804f);
    float f1 = f0 * 0.001f;  // theta^(-16/32) = 1e-3
#pragma unroll
    for (int mi = 0; mi < 2; ++mi)
#pragma unroll
      for (int r = 0; r < 4; ++r) {
        int trow = bm + wr0 + mi * 16 + q4 * 4 + r;
        float x0 = acc[mi][0][r], x1 = acc[mi][1][r], x2 = acc[mi][2][r], x3 = acc[mi][3][r];
        float ss = x0 * x0 + x1 * x1 + x2 * x2 + x3 * x3;
        ss += __shfl_xor(ss, 1);
        ss += __shfl_xor(ss, 2);
        ss += __shfl_xor(ss, 4);
        ss += __shfl_xor(ss, 8);
        float sc = rsqrtf(ss * (1.0f / 64.0f) + 1e-5f);
        float y0 = x0 * sc * wd[0], y1 = x1 * sc * wd[1];
        float y2 = x2 * sc * wd[2], y3 = x3 * sc * wd[3];
        float p = (float)pos[trow];
        float a0 = p * f0, a1 = p * f1;
        float c0 = cosf(a0), s0 = sinf(a0), c1 = cosf(a1), s1 = sinf(a1);
        float o0 = y0 * c0 - y2 * s0, o2 = y2 * c0 + y0 * s0;
        float o1 = y1 * c1 - y3 * s1, o3 = y3 * c1 + y1 * s1;
        bhalf* dst = (h < 32) ? (qo + (size_t)trow * 2048 + h * 64 + m16)
                              : (ko + (size_t)trow * 512 + (h - 32) * 64 + m16);
        dst[0] = (bhalf)o0; dst[16] = (bhalf)o1; dst[32] = (bhalf)o2; dst[48] = (bhalf)o3;
      }
  } else {
#pragma unroll
    for (int mi = 0; mi < 2; ++mi)
#pragma unroll
      for (int r = 0; r < 4; ++r) {
        int trow = bm + wr0 + mi * 16 + q4 * 4 + r;
        bhalf* dst = vo + (size_t)trow * 512 + (h - 40) * 64 + m16;
        dst[0] = (bhalf)acc[mi][0][r]; dst[16] = (bhalf)acc[mi][1][r];
        dst[32] = (bhalf)acc[mi][2][r]; dst[48] = (bhalf)acc[mi][3][r];
      }
  }
}

// ---------------- GEMM2: plain fp32-out epilogue ----------------
__global__ __launch_bounds__(256) void gemm2_k(const bhalf* __restrict__ A,
                                               const bhalf* __restrict__ Bt,
                                               float* __restrict__ C) {
  __shared__ __align__(16) bhalf As[2 * 128 * 64];
  __shared__ __align__(16) bhalf Bs[2 * 64 * 64];
  int tid = threadIdx.x, lane = tid & 63, wv = tid >> 6;
  int m16 = lane & 15, q4 = lane >> 4;
  int bm = blockIdx.y * 128, bn = blockIdx.x * 64;
  f32x4 zero4 = {0.f, 0.f, 0.f, 0.f};
  f32x4 acc[2][4];
#pragma unroll
  for (int mi = 0; mi < 2; ++mi)
#pragma unroll
    for (int ni = 0; ni < 4; ++ni) acc[mi][ni] = zero4;

  gemm_core(A, Bt, HIDN, bm, bn, tid, As, Bs, acc);

  int wr0 = wv * 32;
#pragma unroll
  for (int mi = 0; mi < 2; ++mi)
#pragma unroll
    for (int r = 0; r < 4; ++r) {
      size_t base = (size_t)(bm + wr0 + mi * 16 + q4 * 4 + r) * 2048 + bn + m16;
      C[base] = acc[mi][0][r]; C[base + 16] = acc[mi][1][r];
      C[base + 32] = acc[mi][2][r]; C[base + 48] = acc[mi][3][r];
    }
}

// ---------------- flash attention (causal GQA), fixed-max softmax ----------------
// grid (NQH, 32): block = (head, 64 q-rows), qt = 31 - by (heavy first).
// 4 waves; wave owns 16 q-rows. s-chunk 64, K/V^T double-buffered via
// global_load_lds + XOR swizzle, 1 barrier/chunk.
// SWAPPED QK^T: sv = mfma(K, Q) so lane (m16,q4) holds score(qrow=m16,
// kcol=st*16+q4*4+r) -> P written as packed bhalf4 (ds_write_b64, 4/chunk
// instead of 16 scalar b16), scalar psum per lane, 2-shuffle reduction.
__global__ __launch_bounds__(256) void attn_k(const bhalf* __restrict__ q,
                                              const bhalf* __restrict__ k,
                                              const bhalf* __restrict__ vt,
                                              bhalf* __restrict__ o) {
  __shared__ __align__(16) bhalf Kb[2][4096];
  __shared__ __align__(16) bhalf Vb[2][4096];
  __shared__ __align__(16) bhalf Pb[4][16][72];
  int tid = threadIdx.x, lane = tid & 63, w = tid >> 6;
  int h = blockIdx.x, kh = h >> 2;
  int qt = 31 - blockIdx.y;
  int qb = qt * 64;
  int m16 = lane & 15, q4 = lane >> 4;
  int wrow0 = qb + w * 16;

  const float C1 = 0.18033688011112042f;  // 0.125 * log2(e)
  const float C2 = 11.541560327111707f;   // 8 * log2(e)

  const bhalf* qp = q + (size_t)(wrow0 + m16) * 2048 + h * 64;
  bhalf8 qf0 = *(const bhalf8*)(qp + q4 * 8);
  bhalf8 qf1 = *(const bhalf8*)(qp + 32 + q4 * 8);

  int srow = tid >> 3;
  int scol = ((tid & 7) ^ (srow & 7)) * 8;
  const bhalf* ksrc = k + (size_t)srow * 512 + kh * 64 + scol;
  const bhalf* vsrc = vt + (size_t)(kh * 64 + srow) * 2048 + scol;
  bhalf* kdst = &Kb[0][0] + w * 512;
  bhalf* vdst = &Vb[0][0] + w * 512;

  auto stage = [&](int c) {
    int buf = c & 1, s0 = c * 64;
#pragma unroll
    for (int j = 0; j < 2; ++j) {
      __builtin_amdgcn_global_load_lds((gas_p)(ksrc + (size_t)(s0 + j * 32) * 512),
                                       (las_p)(kdst + buf * 4096 + j * 2048), 16, 0, 0);
      __builtin_amdgcn_global_load_lds((gas_p)(vsrc + (size_t)(j * 32) * 2048 + s0),
                                       (las_p)(vdst + buf * 4096 + j * 2048), 16, 0, 0);
    }
  };

  f32x4 zero4 = {0.f, 0.f, 0.f, 0.f};
  f32x4 oac[4];
  float psum = 0.f;
#pragma unroll
  for (int ni = 0; ni < 4; ++ni) oac[ni] = zero4;
  int swz = m16 & 7;
  bhalf* pwr = &Pb[w][m16][q4 * 4];        // P write base (+ st*16)
  const bhalf* par = &Pb[w][m16][q4 * 8];  // PV A-frag base (+32 for ap1)

  stage(0);
  for (int c = 0; c <= qt; ++c) {
    __syncthreads();  // implicit vmcnt(0) drain: buf c ready, prior buf reads done
    if (c < qt) stage(c + 1);
    int buf = c & 1, s0 = c * 64;
    if (c < qt) {
      // -------- interior chunk: fully unmasked --------
      bhalf8 kf[4][2];
#pragma unroll
      for (int st = 0; st < 4; ++st)
#pragma unroll
        for (int ks = 0; ks < 2; ++ks)
          kf[st][ks] = *(const bhalf8*)&Kb[buf][(st * 16 + m16) * 64 + (((ks * 4 + q4) ^ swz) * 8)];
      f32x4 sv[4];
      __builtin_amdgcn_s_setprio(1);
#pragma unroll
      for (int st = 0; st < 4; ++st) {
        f32x4 t0 = __builtin_amdgcn_mfma_f32_16x16x32_bf16(kf[st][0], qf0, zero4, 0, 0, 0);
        sv[st] = __builtin_amdgcn_mfma_f32_16x16x32_bf16(kf[st][1], qf1, t0, 0, 0, 0);
      }
      __builtin_amdgcn_s_setprio(0);
#pragma unroll
      for (int st = 0; st < 4; ++st) {
        bhalf4 pk;
#pragma unroll
        for (int r = 0; r < 4; ++r) {
          float pe = exp2f(sv[st][r] * C1 - C2);
          psum += pe;
          pk[r] = (bhalf)pe;
        }
        *(bhalf4*)(pwr + st * 16) = pk;
      }
      bhalf8 vf[4][2];
#pragma unroll
      for (int ni = 0; ni < 4; ++ni)
#pragma unroll
        for (int ks = 0; ks < 2; ++ks)
          vf[ni][ks] = *(const bhalf8*)&Vb[buf][(ni * 16 + m16) * 64 + (((ks * 4 + q4) ^ swz) * 8)];
      bhalf8 ap0 = *(const bhalf8*)par;
      bhalf8 ap1 = *(const bhalf8*)(par + 32);
      __builtin_amdgcn_s_setprio(1);
#pragma unroll
      for (int ni = 0; ni < 4; ++ni) {
        oac[ni] = __builtin_amdgcn_mfma_f32_16x16x32_bf16(ap0, vf[ni][0], oac[ni], 0, 0, 0);
        oac[ni] = __builtin_amdgcn_mfma_f32_16x16x32_bf16(ap1, vf[ni][1], oac[ni], 0, 0, 0);
      }
      __builtin_amdgcn_s_setprio(0);
    } else {
      // -------- diagonal chunk: wave w needs st 0..w --------
      bhalf8 kf[4][2];
      f32x4 sv[4];
#pragma unroll
      for (int st = 0; st < 4; ++st)
        if (st <= w) {
#pragma unroll
          for (int ks = 0; ks < 2; ++ks)
            kf[st][ks] = *(const bhalf8*)&Kb[buf][(st * 16 + m16) * 64 + (((ks * 4 + q4) ^ swz) * 8)];
          f32x4 t0 = __builtin_amdgcn_mfma_f32_16x16x32_bf16(kf[st][0], qf0, zero4, 0, 0, 0);
          sv[st] = __builtin_amdgcn_mfma_f32_16x16x32_bf16(kf[st][1], qf1, t0, 0, 0, 0);
        }
      int stwr = (w >= 2) ? 3 : 1;
#pragma unroll
      for (int st = 0; st < 4; ++st) {
        if (st > stwr) continue;
        bhalf4 pk;
#pragma unroll
        for (int r = 0; r < 4; ++r) {
          float pe = 0.f;
          if (st < w) {
            pe = exp2f(sv[st][r] * C1 - C2);
          } else if (st == w) {
            // kcol_local (q4*4+r) vs qrow_local (m16), same 16-block
            pe = (q4 * 4 + r <= m16) ? exp2f(sv[st][r] * C1 - C2) : 0.f;
          }
          psum += pe;
          pk[r] = (bhalf)pe;
        }
        *(bhalf4*)(pwr + st * 16) = pk;
      }
      int ksmax = (w >= 2) ? 1 : 0;
      bhalf8 vf[4][2];
#pragma unroll
      for (int ni = 0; ni < 4; ++ni)
#pragma unroll
        for (int ks = 0; ks < 2; ++ks)
          if (ks <= ksmax)
            vf[ni][ks] = *(const bhalf8*)&Vb[buf][(ni * 16 + m16) * 64 + (((ks * 4 + q4) ^ swz) * 8)];
      bhalf8 ap0 = *(const bhalf8*)par;
#pragma unroll
      for (int ni = 0; ni < 4; ++ni)
        oac[ni] = __builtin_amdgcn_mfma_f32_16x16x32_bf16(ap0, vf[ni][0], oac[ni], 0, 0, 0);
      if (ksmax) {
        bhalf8 ap1 = *(const bhalf8*)(par + 32);
#pragma unroll
        for (int ni = 0; ni < 4; ++ni)
          oac[ni] = __builtin_amdgcn_mfma_f32_16x16x32_bf16(ap1, vf[ni][1], oac[ni], 0, 0, 0);
      }
    }
  }
  // lane holds psum partial for qrow = m16 (its q4 slice); reduce over q4
  psum += __shfl_xor(psum, 16);
  psum += __shfl_xor(psum, 32);
  float inv = 1.0f / psum;  // valid for qrow = m16 on every lane
  // redistribute to PV output layout (qrow = q4*4+r)
  float invr[4];
#pragma unroll
  for (int r = 0; r < 4; ++r) invr[r] = __shfl(inv, q4 * 4 + r);
#pragma unroll
  for (int ni = 0; ni < 4; ++ni)
#pragma unroll
    for (int r = 0; r < 4; ++r) {
      int trow = wrow0 + q4 * 4 + r;
      o[(size_t)trow * 2048 + h * 64 + ni * 16 + m16] = (bhalf)(oac[ni][r] * invr[r]);
    }
}

extern "C" void kernel_launch(void* const* d_in, const int* in_sizes, int n_in,
                              void* d_out, int out_size, void* d_ws, size_t ws_size,
                              hipStream_t stream) {
  const int* positions = (const int*)d_in[0];
  const float* hidden  = (const float*)d_in[1];
  const float* w_qkv   = (const float*)d_in[2];
  const float* w_out   = (const float*)d_in[3];
  const float* q_ln    = (const float*)d_in[4];
  const float* k_ln    = (const float*)d_in[5];
  float* out = (float*)d_out;

  char* wsp = (char*)d_ws;
  bhalf* hid_bf  = (bhalf*)(wsp);                 //  8,388,608 B
  bhalf* wqkvT   = (bhalf*)(wsp + 8388608);       // 12,582,912 B (3072 x 2048)
  bhalf* woutT   = (bhalf*)(wsp + 20971520);      //  8,388,608 B (2048 x 2048)
  bhalf* q_bf    = (bhalf*)(wsp + 29360128);      //  8,388,608 B
  bhalf* k_bf    = (bhalf*)(wsp + 37748736);      //  2,097,152 B
  bhalf* v_bf    = (bhalf*)(wsp + 39845888);      //  2,097,152 B
  bhalf* vt_g    = (bhalf*)(wsp + 41943040);      //  2,097,152 B
  bhalf* attn_bf = (bhalf*)(wsp + 44040192);      //  8,388,608 B (ends 52.4 MB)

  cast_bf16_k<<<T_SEQ * HIDN / 1024, 256, 0, stream>>>(hidden, hid_bf, T_SEQ * HIDN);
  transpose_cast_k<<<dim3(NQKV / 32, HIDN / 32), 256, 0, stream>>>(w_qkv, wqkvT, HIDN, NQKV);
  transpose_cast_k<<<dim3(HIDN / 32, HIDN / 32), 256, 0, stream>>>(w_out, woutT, HIDN, HIDN);
  gemm1_fused_k<<<dim3(NQKV / 64, T_SEQ / 128), 256, 0, stream>>>(
      hid_bf, wqkvT, positions, q_ln, k_ln, q_bf, k_bf, v_bf);
  transpose_bf16_k<<<dim3(512 / 32, T_SEQ / 32), 256, 0, stream>>>(v_bf, vt_g, T_SEQ, 512);
  attn_k<<<dim3(NQH, 32), 256, 0, stream>>>(q_bf, k_bf, vt_g, attn_bf);
  gemm2_k<<<dim3(HIDN / 64, T_SEQ / 128), 256, 0, stream>>>(attn_bf, woutT, out);
}

// Round 3
// 217.379 us; speedup vs baseline: 1.0334x; 1.0212x over previous
//
#include <hip/hip_runtime.h>

typedef __bf16 bhalf;
typedef __bf16 bhalf8 __attribute__((ext_vector_type(8)));
typedef __bf16 bhalf4 __attribute__((ext_vector_type(4)));
typedef float f32x4 __attribute__((ext_vector_type(4)));

typedef __attribute__((address_space(1))) const void* gas_p;
typedef __attribute__((address_space(3))) void* las_p;

#define T_SEQ 2048
#define HIDN  2048
#define NQH   32
#define NKVH  8
#define DH    64
#define NQKV  3072

// ---------------- elementwise cast fp32 -> bf16 ----------------
__global__ __launch_bounds__(256) void cast_bf16_k(const float* __restrict__ in,
                                                   bhalf* __restrict__ out, int n) {
  int i = (blockIdx.x * 256 + threadIdx.x) * 4;
  if (i + 3 < n) {
    float4 v = *(const float4*)(in + i);
    bhalf4 o;
    o[0] = (bhalf)v.x; o[1] = (bhalf)v.y; o[2] = (bhalf)v.z; o[3] = (bhalf)v.w;
    *(bhalf4*)(out + i) = o;
  }
}

// ---------------- transpose + cast fp32->bf16: out[C][R] = (bf16) in[R][C] -------------
__global__ __launch_bounds__(256) void transpose_cast_k(const float* __restrict__ in,
                                                        bhalf* __restrict__ out, int R, int C) {
  __shared__ float tile[32][33];
  int bx = blockIdx.x * 32;
  int by = blockIdx.y * 32;
  int tx = threadIdx.x & 31, ty = threadIdx.x >> 5;
#pragma unroll
  for (int p = 0; p < 4; ++p)
    tile[ty + 8 * p][tx] = in[(size_t)(by + ty + 8 * p) * C + bx + tx];
  __syncthreads();
#pragma unroll
  for (int p = 0; p < 4; ++p)
    out[(size_t)(bx + ty + 8 * p) * R + by + tx] = (bhalf)tile[tx][ty + 8 * p];
}

// ---------------- shared GEMM core: 128(M) x 64(N) tile, BK=64, double-buffered ----------------
__device__ __forceinline__ void gemm_core(const bhalf* __restrict__ A,
                                          const bhalf* __restrict__ Bt, int K,
                                          int bm, int bn, int tid,
                                          bhalf* As, bhalf* Bs, f32x4 acc[2][4]) {
  int lane = tid & 63, wv = tid >> 6;
  int m16 = lane & 15, q4 = lane >> 4;
  int srow = tid >> 3;                         // 0..31
  int scol = ((tid & 7) ^ (srow & 7)) * 8;     // XOR-swizzled source col block
  const bhalf* asrc = A + (size_t)(bm + srow) * K + scol;
  const bhalf* bsrc = Bt + (size_t)(bn + srow) * K + scol;
  bhalf* adst = As + (wv * 8) * 64;
  bhalf* bdst = Bs + (wv * 8) * 64;
  int swz = m16 & 7;

  auto stage = [&](int k0, int sbuf) {
#pragma unroll
    for (int c = 0; c < 4; ++c)
      __builtin_amdgcn_global_load_lds((gas_p)(asrc + (size_t)(c * 32) * K + k0),
                                       (las_p)(adst + sbuf * 8192 + c * 2048), 16, 0, 0);
#pragma unroll
    for (int c = 0; c < 2; ++c)
      __builtin_amdgcn_global_load_lds((gas_p)(bsrc + (size_t)(c * 32) * K + k0),
                                       (las_p)(bdst + sbuf * 4096 + c * 2048), 16, 0, 0);
  };

  stage(0, 0);
  int buf = 0;
  for (int k0 = 0; k0 < K; k0 += 64) {
    __syncthreads();  // drains vmcnt: buf's tile landed (issued one iter ago)
    if (k0 + 64 < K) stage(k0 + 64, buf ^ 1);
    const bhalf* Ab = As + buf * 8192;
    const bhalf* Bb = Bs + buf * 4096;
    bhalf8 af[2][2], bf[4][2];
#pragma unroll
    for (int mi = 0; mi < 2; ++mi)
#pragma unroll
      for (int ks = 0; ks < 2; ++ks)
        af[mi][ks] = *(const bhalf8*)&Ab[(wv * 32 + mi * 16 + m16) * 64 +
                                         (((ks * 4 + q4) ^ swz) * 8)];
#pragma unroll
    for (int ni = 0; ni < 4; ++ni)
#pragma unroll
      for (int ks = 0; ks < 2; ++ks)
        bf[ni][ks] = *(const bhalf8*)&Bb[(ni * 16 + m16) * 64 +
                                         (((ks * 4 + q4) ^ swz) * 8)];
#pragma unroll
    for (int mi = 0; mi < 2; ++mi)
#pragma unroll
      for (int ni = 0; ni < 4; ++ni) {
        acc[mi][ni] = __builtin_amdgcn_mfma_f32_16x16x32_bf16(af[mi][0], bf[ni][0], acc[mi][ni], 0, 0, 0);
        acc[mi][ni] = __builtin_amdgcn_mfma_f32_16x16x32_bf16(af[mi][1], bf[ni][1], acc[mi][ni], 0, 0, 0);
      }
    buf ^= 1;
  }
}

// ---------------- GEMM1 + fused RMSNorm + RoPE + split + cast + V-transpose ----------------
// N-tile 64 == one head (h = blockIdx.x: 0..31 q, 32..39 k, 40..47 v).
// Q heads are pre-scaled by 0.125*log2(e) (folded into RMSNorm weight) so attn's
// softmax is a bare exp2.  V is written directly transposed into vt[512][2048].
__global__ __launch_bounds__(256) void gemm1_fused_k(const bhalf* __restrict__ A,
                                                     const bhalf* __restrict__ Bt,
                                                     const int* __restrict__ pos,
                                                     const float* __restrict__ qw,
                                                     const float* __restrict__ kw,
                                                     bhalf* __restrict__ qo,
                                                     bhalf* __restrict__ ko,
                                                     bhalf* __restrict__ vt) {
  __shared__ __align__(16) bhalf As[2 * 128 * 64];
  __shared__ __align__(16) bhalf Bs[2 * 64 * 64];
  int tid = threadIdx.x, lane = tid & 63, wv = tid >> 6;
  int m16 = lane & 15, q4 = lane >> 4;
  int bm = blockIdx.y * 128, bn = blockIdx.x * 64, h = blockIdx.x;
  f32x4 zero4 = {0.f, 0.f, 0.f, 0.f};
  f32x4 acc[2][4];
#pragma unroll
  for (int mi = 0; mi < 2; ++mi)
#pragma unroll
    for (int ni = 0; ni < 4; ++ni) acc[mi][ni] = zero4;

  gemm_core(A, Bt, HIDN, bm, bn, tid, As, Bs, acc);

  int wr0 = wv * 32;
  if (h < 40) {
    float wd[4];
    const float* wptr = (h < 32) ? qw : kw;
    float wscale = (h < 32) ? 0.18033688011112042f : 1.0f;  // 0.125*log2(e) for Q
#pragma unroll
    for (int ni = 0; ni < 4; ++ni) wd[ni] = wptr[ni * 16 + m16] * wscale;
    float f0 = exp2f((float)m16 * -0.6228615177913804f);
    float f1 = f0 * 0.001f;  // theta^(-16/32) = 1e-3
#pragma unroll
    for (int mi = 0; mi < 2; ++mi)
#pragma unroll
      for (int r = 0; r < 4; ++r) {
        int trow = bm + wr0 + mi * 16 + q4 * 4 + r;
        float x0 = acc[mi][0][r], x1 = acc[mi][1][r], x2 = acc[mi][2][r], x3 = acc[mi][3][r];
        float ss = x0 * x0 + x1 * x1 + x2 * x2 + x3 * x3;
        ss += __shfl_xor(ss, 1);
        ss += __shfl_xor(ss, 2);
        ss += __shfl_xor(ss, 4);
        ss += __shfl_xor(ss, 8);
        float sc = rsqrtf(ss * (1.0f / 64.0f) + 1e-5f);
        float y0 = x0 * sc * wd[0], y1 = x1 * sc * wd[1];
        float y2 = x2 * sc * wd[2], y3 = x3 * sc * wd[3];
        float p = (float)pos[trow];
        float a0 = p * f0, a1 = p * f1;
        float c0 = cosf(a0), s0 = sinf(a0), c1 = cosf(a1), s1 = sinf(a1);
        float o0 = y0 * c0 - y2 * s0, o2 = y2 * c0 + y0 * s0;
        float o1 = y1 * c1 - y3 * s1, o3 = y3 * c1 + y1 * s1;
        bhalf* dst = (h < 32) ? (qo + (size_t)trow * 2048 + h * 64 + m16)
                              : (ko + (size_t)trow * 512 + (h - 32) * 64 + m16);
        dst[0] = (bhalf)o0; dst[16] = (bhalf)o1; dst[32] = (bhalf)o2; dst[48] = (bhalf)o3;
      }
  } else {
    // V head: write directly transposed -> vt[(h-40)*64 + d][t], packed 4 t's per store
#pragma unroll
    for (int mi = 0; mi < 2; ++mi)
#pragma unroll
      for (int ni = 0; ni < 4; ++ni) {
        int trow0 = bm + wr0 + mi * 16 + q4 * 4;
        int d = (h - 40) * 64 + ni * 16 + m16;
        bhalf4 pk;
        pk[0] = (bhalf)acc[mi][ni][0]; pk[1] = (bhalf)acc[mi][ni][1];
        pk[2] = (bhalf)acc[mi][ni][2]; pk[3] = (bhalf)acc[mi][ni][3];
        *(bhalf4*)(vt + (size_t)d * 2048 + trow0) = pk;
      }
  }
}

// ---------------- GEMM2: plain fp32-out epilogue ----------------
__global__ __launch_bounds__(256) void gemm2_k(const bhalf* __restrict__ A,
                                               const bhalf* __restrict__ Bt,
                                               float* __restrict__ C) {
  __shared__ __align__(16) bhalf As[2 * 128 * 64];
  __shared__ __align__(16) bhalf Bs[2 * 64 * 64];
  int tid = threadIdx.x, lane = tid & 63, wv = tid >> 6;
  int m16 = lane & 15, q4 = lane >> 4;
  int bm = blockIdx.y * 128, bn = blockIdx.x * 64;
  f32x4 zero4 = {0.f, 0.f, 0.f, 0.f};
  f32x4 acc[2][4];
#pragma unroll
  for (int mi = 0; mi < 2; ++mi)
#pragma unroll
    for (int ni = 0; ni < 4; ++ni) acc[mi][ni] = zero4;

  gemm_core(A, Bt, HIDN, bm, bn, tid, As, Bs, acc);

  int wr0 = wv * 32;
#pragma unroll
  for (int mi = 0; mi < 2; ++mi)
#pragma unroll
    for (int r = 0; r < 4; ++r) {
      size_t base = (size_t)(bm + wr0 + mi * 16 + q4 * 4 + r) * 2048 + bn + m16;
      C[base] = acc[mi][0][r]; C[base + 16] = acc[mi][1][r];
      C[base + 32] = acc[mi][2][r]; C[base + 48] = acc[mi][3][r];
    }
}

// ---------------- flash attention (causal GQA), fixed-max softmax ----------------
// grid (NQH, 32): block = (head, 64 q-rows), qt = 31 - by (heavy first).
// Q pre-scaled by 0.125*log2(e) in gemm1 -> pe = exp2(sv) directly (no fma, no C2;
// the fixed-max constant cancels in pe/psum; pe <= 2^11.6, psum/oac safe in f32).
// Pb shrunk to [4][16][64] with granule-XOR swizzle (granule ^= m16&7, 8-elem
// granules) -> LDS exactly 40960 B -> 4 blocks/CU (was 3).
__global__ __launch_bounds__(256) void attn_k(const bhalf* __restrict__ q,
                                              const bhalf* __restrict__ k,
                                              const bhalf* __restrict__ vt,
                                              bhalf* __restrict__ o) {
  __shared__ __align__(16) bhalf Kb[2][4096];
  __shared__ __align__(16) bhalf Vb[2][4096];
  __shared__ __align__(16) bhalf Pb[4][16][64];
  int tid = threadIdx.x, lane = tid & 63, w = tid >> 6;
  int h = blockIdx.x, kh = h >> 2;
  int qt = 31 - blockIdx.y;
  int qb = qt * 64;
  int m16 = lane & 15, q4 = lane >> 4;
  int wrow0 = qb + w * 16;

  const bhalf* qp = q + (size_t)(wrow0 + m16) * 2048 + h * 64;
  bhalf8 qf0 = *(const bhalf8*)(qp + q4 * 8);
  bhalf8 qf1 = *(const bhalf8*)(qp + 32 + q4 * 8);

  int srow = tid >> 3;
  int scol = ((tid & 7) ^ (srow & 7)) * 8;
  const bhalf* ksrc = k + (size_t)srow * 512 + kh * 64 + scol;
  const bhalf* vsrc = vt + (size_t)(kh * 64 + srow) * 2048 + scol;
  bhalf* kdst = &Kb[0][0] + w * 512;
  bhalf* vdst = &Vb[0][0] + w * 512;

  auto stage = [&](int c) {
    int buf = c & 1, s0 = c * 64;
#pragma unroll
    for (int j = 0; j < 2; ++j) {
      __builtin_amdgcn_global_load_lds((gas_p)(ksrc + (size_t)(s0 + j * 32) * 512),
                                       (las_p)(kdst + buf * 4096 + j * 2048), 16, 0, 0);
      __builtin_amdgcn_global_load_lds((gas_p)(vsrc + (size_t)(j * 32) * 2048 + s0),
                                       (las_p)(vdst + buf * 4096 + j * 2048), 16, 0, 0);
    }
  };

  f32x4 zero4 = {0.f, 0.f, 0.f, 0.f};
  f32x4 oac[4];
  float psum = 0.f;
#pragma unroll
  for (int ni = 0; ni < 4; ++ni) oac[ni] = zero4;
  int swz = m16 & 7;
  // P granule swizzle: col c lives in granule (c>>3)^swz at offset c&7.
  bhalf* prow = &Pb[w][m16][0];
  int woff = (q4 & 1) << 2;                 // within-granule offset for writes

  stage(0);
  for (int c = 0; c <= qt; ++c) {
    __syncthreads();  // implicit vmcnt(0) drain: buf c ready, prior buf reads done
    if (c < qt) stage(c + 1);
    int buf = c & 1;
    if (c < qt) {
      // -------- interior chunk: fully unmasked --------
      bhalf8 kf[4][2];
#pragma unroll
      for (int st = 0; st < 4; ++st)
#pragma unroll
        for (int ks = 0; ks < 2; ++ks)
          kf[st][ks] = *(const bhalf8*)&Kb[buf][(st * 16 + m16) * 64 + (((ks * 4 + q4) ^ swz) * 8)];
      f32x4 sv[4];
      __builtin_amdgcn_s_setprio(1);
#pragma unroll
      for (int st = 0; st < 4; ++st) {
        f32x4 t0 = __builtin_amdgcn_mfma_f32_16x16x32_bf16(kf[st][0], qf0, zero4, 0, 0, 0);
        sv[st] = __builtin_amdgcn_mfma_f32_16x16x32_bf16(kf[st][1], qf1, t0, 0, 0, 0);
      }
      __builtin_amdgcn_s_setprio(0);
#pragma unroll
      for (int st = 0; st < 4; ++st) {
        bhalf4 pk;
#pragma unroll
        for (int r = 0; r < 4; ++r) {
          float pe = exp2f(sv[st][r]);
          psum += pe;
          pk[r] = (bhalf)pe;
        }
        *(bhalf4*)(prow + ((((2 * st + (q4 >> 1)) ^ swz) << 3) + woff)) = pk;
      }
      bhalf8 vf[4][2];
#pragma unroll
      for (int ni = 0; ni < 4; ++ni)
#pragma unroll
        for (int ks = 0; ks < 2; ++ks)
          vf[ni][ks] = *(const bhalf8*)&Vb[buf][(ni * 16 + m16) * 64 + (((ks * 4 + q4) ^ swz) * 8)];
      bhalf8 ap0 = *(const bhalf8*)(prow + ((q4 ^ swz) << 3));
      bhalf8 ap1 = *(const bhalf8*)(prow + (((4 + q4) ^ swz) << 3));
      __builtin_amdgcn_s_setprio(1);
#pragma unroll
      for (int ni = 0; ni < 4; ++ni) {
        oac[ni] = __builtin_amdgcn_mfma_f32_16x16x32_bf16(ap0, vf[ni][0], oac[ni], 0, 0, 0);
        oac[ni] = __builtin_amdgcn_mfma_f32_16x16x32_bf16(ap1, vf[ni][1], oac[ni], 0, 0, 0);
      }
      __builtin_amdgcn_s_setprio(0);
    } else {
      // -------- diagonal chunk: wave w needs st 0..w --------
      bhalf8 kf[4][2];
      f32x4 sv[4];
#pragma unroll
      for (int st = 0; st < 4; ++st)
        if (st <= w) {
#pragma unroll
          for (int ks = 0; ks < 2; ++ks)
            kf[st][ks] = *(const bhalf8*)&Kb[buf][(st * 16 + m16) * 64 + (((ks * 4 + q4) ^ swz) * 8)];
          f32x4 t0 = __builtin_amdgcn_mfma_f32_16x16x32_bf16(kf[st][0], qf0, zero4, 0, 0, 0);
          sv[st] = __builtin_amdgcn_mfma_f32_16x16x32_bf16(kf[st][1], qf1, t0, 0, 0, 0);
        }
      int stwr = (w >= 2) ? 3 : 1;
#pragma unroll
      for (int st = 0; st < 4; ++st) {
        if (st > stwr) continue;
        bhalf4 pk;
#pragma unroll
        for (int r = 0; r < 4; ++r) {
          float pe = 0.f;
          if (st < w) {
            pe = exp2f(sv[st][r]);
          } else if (st == w) {
            // kcol_local (q4*4+r) vs qrow_local (m16), same 16-block
            pe = (q4 * 4 + r <= m16) ? exp2f(sv[st][r]) : 0.f;
          }
          psum += pe;
          pk[r] = (bhalf)pe;
        }
        *(bhalf4*)(prow + ((((2 * st + (q4 >> 1)) ^ swz) << 3) + woff)) = pk;
      }
      int ksmax = (w >= 2) ? 1 : 0;
      bhalf8 vf[4][2];
#pragma unroll
      for (int ni = 0; ni < 4; ++ni)
#pragma unroll
        for (int ks = 0; ks < 2; ++ks)
          if (ks <= ksmax)
            vf[ni][ks] = *(const bhalf8*)&Vb[buf][(ni * 16 + m16) * 64 + (((ks * 4 + q4) ^ swz) * 8)];
      bhalf8 ap0 = *(const bhalf8*)(prow + ((q4 ^ swz) << 3));
#pragma unroll
      for (int ni = 0; ni < 4; ++ni)
        oac[ni] = __builtin_amdgcn_mfma_f32_16x16x32_bf16(ap0, vf[ni][0], oac[ni], 0, 0, 0);
      if (ksmax) {
        bhalf8 ap1 = *(const bhalf8*)(prow + (((4 + q4) ^ swz) << 3));
#pragma unroll
        for (int ni = 0; ni < 4; ++ni)
          oac[ni] = __builtin_amdgcn_mfma_f32_16x16x32_bf16(ap1, vf[ni][1], oac[ni], 0, 0, 0);
      }
    }
  }
  // lane holds psum partial for qrow = m16 (its q4 slice); reduce over q4
  psum += __shfl_xor(psum, 16);
  psum += __shfl_xor(psum, 32);
  float inv = 1.0f / psum;  // valid for qrow = m16 on every lane
  // redistribute to PV output layout (qrow = q4*4+r)
  float invr[4];
#pragma unroll
  for (int r = 0; r < 4; ++r) invr[r] = __shfl(inv, q4 * 4 + r);
#pragma unroll
  for (int ni = 0; ni < 4; ++ni)
#pragma unroll
    for (int r = 0; r < 4; ++r) {
      int trow = wrow0 + q4 * 4 + r;
      o[(size_t)trow * 2048 + h * 64 + ni * 16 + m16] = (bhalf)(oac[ni][r] * invr[r]);
    }
}

extern "C" void kernel_launch(void* const* d_in, const int* in_sizes, int n_in,
                              void* d_out, int out_size, void* d_ws, size_t ws_size,
                              hipStream_t stream) {
  const int* positions = (const int*)d_in[0];
  const float* hidden  = (const float*)d_in[1];
  const float* w_qkv   = (const float*)d_in[2];
  const float* w_out   = (const float*)d_in[3];
  const float* q_ln    = (const float*)d_in[4];
  const float* k_ln    = (const float*)d_in[5];
  float* out = (float*)d_out;

  char* wsp = (char*)d_ws;
  bhalf* hid_bf  = (bhalf*)(wsp);                 //  8,388,608 B
  bhalf* wqkvT   = (bhalf*)(wsp + 8388608);       // 12,582,912 B (3072 x 2048)
  bhalf* woutT   = (bhalf*)(wsp + 20971520);      //  8,388,608 B (2048 x 2048)
  bhalf* q_bf    = (bhalf*)(wsp + 29360128);      //  8,388,608 B
  bhalf* k_bf    = (bhalf*)(wsp + 37748736);      //  2,097,152 B
  bhalf* vt_g    = (bhalf*)(wsp + 41943040);      //  2,097,152 B (written by gemm1)
  bhalf* attn_bf = (bhalf*)(wsp + 44040192);      //  8,388,608 B (ends 52.4 MB)

  cast_bf16_k<<<T_SEQ * HIDN / 1024, 256, 0, stream>>>(hidden, hid_bf, T_SEQ * HIDN);
  transpose_cast_k<<<dim3(NQKV / 32, HIDN / 32), 256, 0, stream>>>(w_qkv, wqkvT, HIDN, NQKV);
  transpose_cast_k<<<dim3(HIDN / 32, HIDN / 32), 256, 0, stream>>>(w_out, woutT, HIDN, HIDN);
  gemm1_fused_k<<<dim3(NQKV / 64, T_SEQ / 128), 256, 0, stream>>>(
      hid_bf, wqkvT, positions, q_ln, k_ln, q_bf, k_bf, vt_g);
  attn_k<<<dim3(NQH, 32), 256, 0, stream>>>(q_bf, k_bf, vt_g, attn_bf);
  gemm2_k<<<dim3(HIDN / 64, T_SEQ / 128), 256, 0, stream>>>(attn_bf, woutT, out);
}